// Round 5
// baseline (130.616 us; speedup 1.0000x reference)
//
#include <hip/hip_runtime.h>

#define NSPK 256
#define MUTT 64
#define DDIM 1024
#define NROW (NSPK * MUTT)   // 16384

using frag_ab = __attribute__((ext_vector_type(8))) short;   // 8 bf16 (4 VGPRs)
using frag_cd = __attribute__((ext_vector_type(4))) float;   // 4 fp32 acc

static __device__ __forceinline__ unsigned short f32_to_bf16(float f) {
    unsigned int u = __float_as_uint(f);
    return (unsigned short)((u + 0x7FFFu + ((u >> 16) & 1u)) >> 16);   // RNE
}
static __device__ __forceinline__ unsigned int pack2(float a, float b) {
    return (unsigned)f32_to_bf16(a) | ((unsigned)f32_to_bf16(b) << 16);
}
static __device__ __forceinline__ void gload16(const void* g, void* l) {
    __builtin_amdgcn_global_load_lds(
        (const __attribute__((address_space(1))) unsigned int*)g,
        (__attribute__((address_space(3))) unsigned int*)l, 16, 0, 0);
}

// ======================= FAST PATH =======================

// k_prep: grid (NSPK, 8), 256 thr, 8 rows/block (2048 blocks -> 32 waves/CU).
// Thread t owns 4 columns across 8 rows; emits bf16 cast + per-row q + S partials.
__global__ void __launch_bounds__(256) k_prep(const float* __restrict__ emb,
                                              float* __restrict__ Sp,
                                              unsigned short* __restrict__ ebf,
                                              float* __restrict__ qg) {
    const int j = blockIdx.x;
    const int h = blockIdx.y;
    const int t = threadIdx.x;
    const int lane = t & 63, wave = t >> 6;
    const size_t rowbase = (size_t)j * MUTT + (size_t)h * 8;
    const float* src = emb + rowbase * DDIM + (size_t)t * 4;
    unsigned short* edst = ebf + rowbase * DDIM + (size_t)t * 4;
    __shared__ float qws[8][4];
    float4 s = make_float4(0.f, 0.f, 0.f, 0.f);
    #pragma unroll
    for (int m = 0; m < 8; ++m) {
        float4 v = *(const float4*)(src + (size_t)m * DDIM);
        s.x += v.x; s.y += v.y; s.z += v.z; s.w += v.w;
        float qp = v.x * v.x + v.y * v.y + v.z * v.z + v.w * v.w;
        #pragma unroll
        for (int off = 32; off > 0; off >>= 1) qp += __shfl_down(qp, off, 64);
        if (lane == 0) qws[m][wave] = qp;
        *(uint2*)(edst + (size_t)m * DDIM) = make_uint2(pack2(v.x, v.y), pack2(v.z, v.w));
    }
    __syncthreads();
    if (t < 8) qg[rowbase + t] = qws[t][0] + qws[t][1] + qws[t][2] + qws[t][3];
    *(float4*)(Sp + ((size_t)h * NSPK + j) * DDIM + (size_t)t * 4) = s;
}

template <int P>
__global__ void k_center(const float* __restrict__ Sp, unsigned short* __restrict__ cbf,
                         float* __restrict__ normS2g, float* __restrict__ normSg) {
    const int j = blockIdx.x;
    const int t = threadIdx.x;
    float4 v = make_float4(0.f, 0.f, 0.f, 0.f);
    #pragma unroll
    for (int p = 0; p < P; ++p) {
        float4 a = *(const float4*)(Sp + ((size_t)p * NSPK + j) * DDIM + (size_t)t * 4);
        v.x += a.x; v.y += a.y; v.z += a.z; v.w += a.w;
    }
    float sq = v.x * v.x + v.y * v.y + v.z * v.z + v.w * v.w;
    #pragma unroll
    for (int off = 32; off > 0; off >>= 1) sq += __shfl_down(sq, off, 64);
    __shared__ float ws[4];
    __shared__ float sc_sh;
    const int lane = t & 63, wave = t >> 6;
    if (lane == 0) ws[wave] = sq;
    __syncthreads();
    if (t == 0) {
        float tot = ws[0] + ws[1] + ws[2] + ws[3];
        normS2g[j] = tot;
        normSg[j]  = sqrtf(tot);
        float msq = tot * (1.0f / 4096.0f);
        sc_sh = rsqrtf(fmaxf(msq, 1e-12f)) * (1.0f / 64.0f);
    }
    __syncthreads();
    const float sc = sc_sh;
    *(uint2*)(cbf + (size_t)j * DDIM + (size_t)t * 4) =
        make_uint2(pack2(v.x * sc, v.y * sc), pack2(v.z * sc, v.w * sc));
}

// k_gemm5: B-slab-resident GEMM, NO per-K-step barriers.
// Block = 128 rows x 64 cols, 256 thr (4 waves); wave = 32 rows x 64 cols.
// B (64 cols x 512 k, 64 KB) staged to LDS per K-half via gload16 (global-side XOR
// swizzle so frag ds_read_b128 is conflict-free); A streamed global->reg in-loop.
// Grid (128, 4) = 512 blocks, 2 blocks/CU (LDS-limited), 8 waves/CU.
__global__ void __launch_bounds__(256, 2)
k_gemm5(const unsigned short* __restrict__ ebf, const unsigned short* __restrict__ cbf,
        const float* __restrict__ qg, const float* __restrict__ n2g,
        const float* __restrict__ n1g,
        const float* __restrict__ wp, const float* __restrict__ bp,
        float* __restrict__ out) {
    __shared__ unsigned short Bs[64 * 512];   // 64 KB: 64 cols x half-K

    const int tid = threadIdx.x, lane = tid & 63, wave = tid >> 6;
    const int bx = blockIdx.x;            // row tile: 128 rows = 2 speakers
    const int ct = blockIdx.y;            // 64-col tile
    const int row0 = bx * 128;
    const int c0 = ct * 64;

    const int quad = lane >> 4;
    const int m16 = lane & 15;

    // B staging: wave w stages col (round*4 + w); lane l fetches global chunk (l^s)
    // so that LDS linear chunk p holds global chunk p^s  (s = col&7).
    // A per-lane base: rows wave*32 + {0,16} + m16, k-offset quad*8.
    const char* agbase = (const char*)ebf + ((size_t)(row0 + wave * 32 + m16) * DDIM + quad * 8) * 2;

    frag_cd acc[2][4];
    #pragma unroll
    for (int rr = 0; rr < 2; ++rr)
        #pragma unroll
        for (int cc = 0; cc < 4; ++cc) acc[rr][cc] = (frag_cd){0.f, 0.f, 0.f, 0.f};

    #pragma unroll
    for (int h = 0; h < 2; ++h) {
        if (h) __syncthreads();           // all waves done reading half 0
        // ---- stage B half h: 16 rounds x 256 thr x 16 B ----
        #pragma unroll
        for (int round = 0; round < 16; ++round) {
            const int col = round * 4 + wave;          // 0..63
            const int s = col & 7;
            const char* g = (const char*)cbf +
                (size_t)(c0 + col) * (DDIM * 2) + h * 1024 + ((lane ^ s) << 4);
            gload16(g, (char*)Bs + col * 1024 + (lane << 4));
        }
        __syncthreads();                  // drains gload16 vmcnt

        // ---- barrier-free inner loop over this half's K (512 elems, 16 steps) ----
        #pragma unroll 4
        for (int ks = 0; ks < 16; ++ks) {
            frag_ab af[2], bf[4];
            const int koff = h * 1024 + ks * 64;       // bytes within a row
            af[0] = *(const frag_ab*)(agbase + koff);
            af[1] = *(const frag_ab*)(agbase + 16 * (DDIM * 2) + koff);
            #pragma unroll
            for (int cc = 0; cc < 4; ++cc) {
                const int col = cc * 16 + m16;
                const int chunk = ((ks * 4 + quad) ^ (col & 7));
                bf[cc] = *(const frag_ab*)((const char*)Bs + col * 1024 + (chunk << 4));
            }
            #pragma unroll
            for (int rr = 0; rr < 2; ++rr)
                #pragma unroll
                for (int cc = 0; cc < 4; ++cc)
                    acc[rr][cc] = __builtin_amdgcn_mfma_f32_16x16x32_bf16(
                        af[rr], bf[cc], acc[rr][cc], 0, 0, 0);
        }
    }

    const float wv = wp[0], bv = bp[0];
    #pragma unroll
    for (int rr = 0; rr < 2; ++rr) {
        int rbase = wave * 32 + rr * 16 + (quad << 2);
        #pragma unroll
        for (int cc = 0; cc < 4; ++cc) {
            int col = c0 + cc * 16 + m16;
            frag_cd v = acc[rr][cc];
            #pragma unroll
            for (int r2 = 0; r2 < 4; ++r2) {
                int grow = row0 + rbase + r2;
                float val = v[r2];
                int jspk = grow >> 6;
                if (col == jspk) {
                    float q = qg[grow];
                    float ns2 = n2g[jspk];
                    float ns = n1g[jspk];
                    float rd = val * ns;
                    float den2 = ns2 - 2.f * rd + q;
                    val = (rd - q) * rsqrtf(fmaxf(den2, 1e-12f));
                }
                out[(size_t)grow * NSPK + col] = wv * val + bv;
            }
        }
    }
}

// ======================= FALLBACK (small ws) =======================

__global__ void k_sums(const float* __restrict__ emb, float* __restrict__ Sp) {
    const int j = blockIdx.x;
    const int h = blockIdx.y;
    const int c = threadIdx.x;
    const float* base = emb + ((size_t)j * MUTT + (size_t)h * 32) * DDIM + (size_t)c * 4;
    float4 acc = make_float4(0.f, 0.f, 0.f, 0.f);
    #pragma unroll 8
    for (int m = 0; m < 32; ++m) {
        float4 v = *(const float4*)(base + (size_t)m * DDIM);
        acc.x += v.x; acc.y += v.y; acc.z += v.z; acc.w += v.w;
    }
    *(float4*)(Sp + ((size_t)h * NSPK + j) * DDIM + (size_t)c * 4) = acc;
}

__global__ void __launch_bounds__(256)
k_gemm_old(const float* __restrict__ emb, const unsigned short* __restrict__ cbf,
           const float* __restrict__ normS2g, const float* __restrict__ normSg,
           const float* __restrict__ wp, const float* __restrict__ bp,
           float* __restrict__ out) {
    __shared__ unsigned short Asm[32][32];
    __shared__ unsigned short Bsm[256][32];
    __shared__ float qpart[32][8];
    __shared__ float qfin[32];
    const int tid = threadIdx.x, lane = tid & 63, wave = tid >> 6;
    const int row0 = blockIdx.x * 32;
    const int jspk = row0 >> 6;
    frag_cd acc[2][4];
    #pragma unroll
    for (int rr = 0; rr < 2; ++rr)
        #pragma unroll
        for (int cc = 0; cc < 4; ++cc) acc[rr][cc] = (frag_cd){0.f, 0.f, 0.f, 0.f};
    const int ar = tid >> 3, ak = (tid & 7) << 2;
    const float* aptr = emb + (size_t)(row0 + ar) * DDIM + ak;
    float qacc = 0.f;
    const int bi = tid >> 2, bk = (tid & 3) << 3;
    const int am = lane & 15, kq = (lane >> 4) << 3;
    for (int k0 = 0; k0 < DDIM; k0 += 32) {
        __syncthreads();
        float4 av = *(const float4*)(aptr + k0);
        qacc += av.x * av.x + av.y * av.y + av.z * av.z + av.w * av.w;
        *(uint2*)&Asm[ar][ak] = make_uint2(pack2(av.x, av.y), pack2(av.z, av.w));
        #pragma unroll
        for (int p = 0; p < 4; ++p) {
            int brow = p * 64 + bi;
            *(uint4*)&Bsm[brow][bk] = *(const uint4*)(cbf + (size_t)brow * DDIM + k0 + bk);
        }
        __syncthreads();
        frag_ab afr[2], bfr[4];
        #pragma unroll
        for (int rr = 0; rr < 2; ++rr) afr[rr] = *(const frag_ab*)&Asm[rr * 16 + am][kq];
        #pragma unroll
        for (int cc = 0; cc < 4; ++cc) bfr[cc] = *(const frag_ab*)&Bsm[wave * 64 + cc * 16 + am][kq];
        #pragma unroll
        for (int rr = 0; rr < 2; ++rr)
            #pragma unroll
            for (int cc = 0; cc < 4; ++cc)
                acc[rr][cc] = __builtin_amdgcn_mfma_f32_16x16x32_bf16(afr[rr], bfr[cc], acc[rr][cc], 0, 0, 0);
    }
    qpart[ar][tid & 7] = qacc;
    __syncthreads();
    if (tid < 32) {
        float s = 0.f;
        #pragma unroll
        for (int u = 0; u < 8; ++u) s += qpart[tid][u];
        qfin[tid] = s;
    }
    __syncthreads();
    const float wv = wp[0], bv = bp[0];
    const float ns2 = normS2g[jspk], ns = normSg[jspk];
    #pragma unroll
    for (int rr = 0; rr < 2; ++rr) {
        int rbase = rr * 16 + ((lane >> 4) << 2);
        #pragma unroll
        for (int cc = 0; cc < 4; ++cc) {
            int col = wave * 64 + cc * 16 + (lane & 15);
            frag_cd v = acc[rr][cc];
            #pragma unroll
            for (int r2 = 0; r2 < 4; ++r2) {
                int lrow = rbase + r2;
                float val = v[r2];
                if (col == jspk) {
                    float q = qfin[lrow];
                    float rd = val * ns;
                    float den2 = ns2 - 2.f * rd + q;
                    val = (rd - q) * rsqrtf(fmaxf(den2, 1e-12f));
                }
                out[(size_t)(row0 + lrow) * NSPK + col] = wv * val + bv;
            }
        }
    }
}

extern "C" void kernel_launch(void* const* d_in, const int* in_sizes, int n_in,
                              void* d_out, int out_size, void* d_ws, size_t ws_size,
                              hipStream_t stream) {
    const float* emb = (const float*)d_in[0];
    const float* w   = (const float*)d_in[1];
    const float* b   = (const float*)d_in[2];
    float* out = (float*)d_out;

    const size_t sz_Sp  = (size_t)8 * NSPK * DDIM * 4;
    const size_t sz_ebf = (size_t)NROW * DDIM * 2;
    const size_t sz_cbf = (size_t)NSPK * DDIM * 2;
    const size_t sz_qg  = (size_t)NROW * 4;
    const size_t need = sz_Sp + sz_ebf + sz_cbf + sz_qg + 2 * NSPK * 4;

    if (ws_size >= need) {
        char* p = (char*)d_ws;
        float* Sp = (float*)p;              p += sz_Sp;
        unsigned short* ebf = (unsigned short*)p; p += sz_ebf;
        unsigned short* cbf = (unsigned short*)p; p += sz_cbf;
        float* qg = (float*)p;              p += sz_qg;
        float* n2 = (float*)p;              p += NSPK * 4;
        float* n1 = n2 + NSPK;
        k_prep<<<dim3(NSPK, 8), 256, 0, stream>>>(emb, Sp, ebf, qg);
        k_center<8><<<NSPK, 256, 0, stream>>>(Sp, cbf, n2, n1);
        k_gemm5<<<dim3(NROW / 128, NSPK / 64), 256, 0, stream>>>(ebf, cbf, qg, n2, n1, w, b, out);
    } else {
        float* Sp = (float*)d_ws;
        unsigned short* cbf = (unsigned short*)(Sp + 2 * NSPK * DDIM);
        float* n2 = (float*)(cbf + NSPK * DDIM);
        float* n1 = n2 + NSPK;
        k_sums<<<dim3(NSPK, 2), 256, 0, stream>>>(emb, Sp);
        k_center<2><<<NSPK, 256, 0, stream>>>(Sp, cbf, n2, n1);
        k_gemm_old<<<NROW / 32, 256, 0, stream>>>(emb, cbf, n2, n1, w, b, out);
    }
}